// Round 9
// baseline (262.506 us; speedup 1.0000x reference)
//
#include <hip/hip_runtime.h>
#include <hip/hip_fp16.h>
#include <math.h>

// Problem constants (from reference)
#define BATCH 128
#define NI    1152
#define ND    8
#define NC    32
#define NE    16
#define NROUT 3

// Tiling: 256 threads = 32 c x 2 e-halves x 4 batch-groups; NB=4 batches each
// (proven 72-VGPR shape). ISPLIT=128 -> 1024 blocks = 4 blocks/CU = 16 waves/CU.
// Partial s stored as fp16 (128 slices x 128 KB = 16.4 MB fits ws).
#define ISPLIT     128
#define ICHUNK     (NI / ISPLIT)    // 9
#define BT         16               // batches per block
#define NB         4                // batches per thread
#define RT_THREADS 256
#define WROW       132              // padded row stride: conflict-free (measured 0)
#define SQ_THREADS 256

template<int CTRL>
__device__ __forceinline__ float dpp_add(float v) {
    int t = __builtin_amdgcn_update_dpp(0, __float_as_int(v), CTRL, 0xF, 0xF, true);
    return v + __int_as_float(t);
}

// Sum over lane bits 0..4 (32 'c' lanes of each eh-half).
__device__ __forceinline__ float sum_over_c(float v) {
    v = dpp_add<0xB1>(v);    // lane ^ 1   quad_perm(1,0,3,2)
    v = dpp_add<0x4E>(v);    // lane ^ 2   quad_perm(2,3,0,1)
    v = dpp_add<0x141>(v);   // lane ^ 4   row_half_mirror
    v = dpp_add<0x140>(v);   // lane ^ 8   row_mirror
    int s = __builtin_amdgcn_ds_swizzle(__float_as_int(v), 0x401F); // lane ^ 16
    return v + __int_as_float(s);
}

// Sum over lane bits 0..2 (8 e-pair lanes) for squash (each thread holds 2 e's).
__device__ __forceinline__ float sum_over_e8(float v) {
    v = dpp_add<0xB1>(v);
    v = dpp_add<0x4E>(v);
    v = dpp_add<0x141>(v);
    return v;
}

// Raw barrier: LDS-ordered (lgkmcnt(0)) but does NOT drain vmcnt — global
// prefetch loads stay in flight across it.
__device__ __forceinline__ void lds_barrier() {
    asm volatile("s_waitcnt lgkmcnt(0)" ::: "memory");
    __builtin_amdgcn_s_barrier();
    __builtin_amdgcn_sched_barrier(0);
}

// ---------------------------------------------------------------------------
// Fused routing iteration. W double-buffered in LDS; x and W software-
// pipelined with counted-vmcnt raw barriers. Softmax over c in-wave (DPP + 1
// swizzle). Partial s written fp16-packed, one slice per ic (atomic fp32
// fallback if ws too small).
// ---------------------------------------------------------------------------
__global__ __launch_bounds__(RT_THREADS, 4)
void route_iter_kernel(const float* __restrict__ x, const float* __restrict__ W,
                       const float* __restrict__ o_sum, void* __restrict__ s_part,
                       int iter, int nslice, int use_atomic)
{
    __shared__ float Ws[2][NC * WROW];   // 2 x 16.9 KB

    const int tid = threadIdx.x;
    const int c   = tid & 31;
    const int eh  = (tid >> 5) & 1;
    const int bp  = __builtin_amdgcn_readfirstlane(tid >> 6);  // wave-uniform
    const int ic  = blockIdx.x;
    const int bt  = blockIdx.y;
    const int i0  = ic * ICHUNK;
    const int b0  = bt * BT + bp * NB;   // 4 consecutive batches per wave
    const int e0  = eh * 8;

    // o_sum[b, c, e0..e0+7] in registers (iter > 0 only)
    float o_reg[NB][8];
    if (iter > 0) {
#pragma unroll
        for (int j = 0; j < NB; ++j) {
            const float4* op = (const float4*)(o_sum + ((size_t)(b0 + j) * NC + c) * NE + e0);
            float4 a = op[0], b = op[1];
            o_reg[j][0] = a.x; o_reg[j][1] = a.y; o_reg[j][2] = a.z; o_reg[j][3] = a.w;
            o_reg[j][4] = b.x; o_reg[j][5] = b.y; o_reg[j][6] = b.z; o_reg[j][7] = b.w;
        }
    }

    float s_acc[NB][8];
#pragma unroll
    for (int j = 0; j < NB; ++j)
#pragma unroll
        for (int e = 0; e < 8; ++e) s_acc[j][e] = 0.f;

    // ---- prologue: x(0) in flight; W(0) staged; W(1) in flight ----
    float4 xn[NB][2];
#pragma unroll
    for (int j = 0; j < NB; ++j) {
        const float4* xp = (const float4*)(x + ((size_t)(b0 + j) * NI + i0) * ND);
        xn[j][0] = xp[0];
        xn[j][1] = xp[1];
    }
    float4 pr[4];
    {
        const float4* src = (const float4*)(W + (size_t)i0 * (NC * ND * NE));
#pragma unroll
        for (int r = 0; r < 4; ++r) pr[r] = src[tid + r * RT_THREADS];
#pragma unroll
        for (int r = 0; r < 4; ++r) {
            int j = tid + r * RT_THREADS;            // float4 chunk 0..1023
            *(float4*)&Ws[0][(j >> 5) * WROW + (j & 31) * 4] = pr[r];
        }
    }
    if (ICHUNK > 1) {
        const float4* src = (const float4*)(W + (size_t)(i0 + 1) * (NC * ND * NE));
#pragma unroll
        for (int r = 0; r < 4; ++r) pr[r] = src[tid + r * RT_THREADS];
    }

    for (int ii = 0; ii < ICHUNK; ++ii) {
        lds_barrier();            // Ws[ii&1] ready; no vmcnt drain

        // xv <- xn (counted vmcnt for x(ii); W prefetch stays in flight)
        float xv[NB][ND];
#pragma unroll
        for (int j = 0; j < NB; ++j) {
            xv[j][0] = xn[j][0].x; xv[j][1] = xn[j][0].y;
            xv[j][2] = xn[j][0].z; xv[j][3] = xn[j][0].w;
            xv[j][4] = xn[j][1].x; xv[j][5] = xn[j][1].y;
            xv[j][6] = xn[j][1].z; xv[j][7] = xn[j][1].w;
        }
        // issue x(ii+1)
        if (ii + 1 < ICHUNK) {
#pragma unroll
            for (int j = 0; j < NB; ++j) {
                const float4* xp = (const float4*)(x + ((size_t)(b0 + j) * NI + (i0 + ii + 1)) * ND);
                xn[j][0] = xp[0];
                xn[j][1] = xp[1];
            }
        }

        // ---- u_hat[b0..b0+3, c, e0..e0+7] ----
        const float* wr = &Ws[ii & 1][c * WROW + e0];
        float uh[NB][8];
#pragma unroll
        for (int j = 0; j < NB; ++j)
#pragma unroll
            for (int e = 0; e < 8; ++e) uh[j][e] = 0.f;

#pragma unroll
        for (int d = 0; d < ND; ++d) {
            float4 wa = *(const float4*)(wr + d * 16);
            float4 wb = *(const float4*)(wr + d * 16 + 4);
#pragma unroll
            for (int j = 0; j < NB; ++j) {
                const float xd = xv[j][d];
                uh[j][0] = fmaf(xd, wa.x, uh[j][0]);
                uh[j][1] = fmaf(xd, wa.y, uh[j][1]);
                uh[j][2] = fmaf(xd, wa.z, uh[j][2]);
                uh[j][3] = fmaf(xd, wa.w, uh[j][3]);
                uh[j][4] = fmaf(xd, wb.x, uh[j][4]);
                uh[j][5] = fmaf(xd, wb.y, uh[j][5]);
                uh[j][6] = fmaf(xd, wb.z, uh[j][6]);
                uh[j][7] = fmaf(xd, wb.w, uh[j][7]);
            }
        }

        // ---- routing weights + s accumulation ----
        if (iter > 0) {
#pragma unroll
            for (int j = 0; j < NB; ++j) {
                float lp = 0.f;
#pragma unroll
                for (int e = 0; e < 8; ++e) lp = fmaf(uh[j][e], o_reg[j][e], lp);
                lp += __shfl_xor(lp, 32);          // combine e-halves -> full logit
                float el = __expf(lp);             // |logit| small; no max-sub
                float den = sum_over_c(el);        // softmax denom over 32 c
                float wgt = el / den;
#pragma unroll
                for (int e = 0; e < 8; ++e) s_acc[j][e] = fmaf(wgt, uh[j][e], s_acc[j][e]);
            }
        } else {
            const float wgt = 1.f / 32.f;
#pragma unroll
            for (int j = 0; j < NB; ++j)
#pragma unroll
                for (int e = 0; e < 8; ++e) s_acc[j][e] = fmaf(wgt, uh[j][e], s_acc[j][e]);
        }

        // ---- write W(ii+1) into the other buffer; issue W(ii+2) ----
        if (ii + 1 < ICHUNK) {
#pragma unroll
            for (int r = 0; r < 4; ++r) {
                int j = tid + r * RT_THREADS;
                *(float4*)&Ws[(ii + 1) & 1][(j >> 5) * WROW + (j & 31) * 4] = pr[r];
            }
            if (ii + 2 < ICHUNK) {
                const float4* src = (const float4*)(W + (size_t)(i0 + ii + 2) * (NC * ND * NE));
#pragma unroll
                for (int r = 0; r < 4; ++r) pr[r] = src[tid + r * RT_THREADS];
            }
        }
    }

    // ---- write partial s ----
    if (!use_atomic) {
        __half* sp = (__half*)s_part;
#pragma unroll
        for (int j = 0; j < NB; ++j) {
            __half* base = sp + (((size_t)ic * BATCH + (b0 + j)) * NC + c) * NE + e0;
            union { __half2 h2[4]; uint4 u; } pk;
#pragma unroll
            for (int q = 0; q < 4; ++q)
                pk.h2[q] = __floats2half2_rn(s_acc[j][2*q], s_acc[j][2*q+1]);
            *(uint4*)base = pk.u;   // 16B aligned: (c*16 + e0)*2 bytes
        }
    } else {
        float* sp = (float*)s_part;
        const int slice = ic & (nslice - 1);
#pragma unroll
        for (int j = 0; j < NB; ++j) {
            float* base = sp + (((size_t)slice * BATCH + (b0 + j)) * NC + c) * NE + e0;
#pragma unroll
            for (int e = 0; e < 8; ++e) atomicAdd(base + e, s_acc[j][e]);
        }
    }
}

// ---------------------------------------------------------------------------
// squash: reduce slices (fp16 plain or fp32 atomic layout), squash, update
// o_sum / write output. Each thread owns an e-pair; e-reduction via DPP over
// lane bits 0..2 (8 pairs).
// ---------------------------------------------------------------------------
__global__ __launch_bounds__(SQ_THREADS)
void squash_kernel(void* __restrict__ s_part, float* __restrict__ o_sum,
                   float* __restrict__ out, int iter, int nslice, int use_atomic)
{
    const int base2 = (blockIdx.x * SQ_THREADS + threadIdx.x) * 2;  // element pair

    float a0 = 0.f, a1 = 0.f;
    if (!use_atomic) {
        const __half* sp = (const __half*)s_part;
        for (int k = 0; k < nslice; ++k) {
            __half2 v = *(const __half2*)(sp + (size_t)k * (BATCH * NC * NE) + base2);
            a0 += __low2float(v);
            a1 += __high2float(v);
        }
    } else {
        float* sp = (float*)s_part;
        for (int k = 0; k < nslice; ++k) {
            float2 v = *(float2*)(sp + (size_t)k * (BATCH * NC * NE) + base2);
            a0 += v.x; a1 += v.y;
            *(float2*)(sp + (size_t)k * (BATCH * NC * NE) + base2) = make_float2(0.f, 0.f);
        }
    }

    float q = sum_over_e8(a0 * a0 + a1 * a1);
    // scale = s2/(1+s2)/sqrt(s2) == sqrt(s2)/(1+s2)
    float scale = sqrtf(q) / (1.f + q);
    float o0 = scale * a0, o1 = scale * a1;

    if (iter == NROUT - 1) {
        *(float2*)(out + base2) = make_float2(o0, o1);
    } else if (iter == 0) {
        *(float2*)(o_sum + base2) = make_float2(o0, o1);
    } else {
        float2 prev = *(float2*)(o_sum + base2);
        *(float2*)(o_sum + base2) = make_float2(prev.x + o0, prev.y + o1);
    }
}

extern "C" void kernel_launch(void* const* d_in, const int* in_sizes, int n_in,
                              void* d_out, int out_size, void* d_ws, size_t ws_size,
                              hipStream_t stream) {
    const float* x = (const float*)d_in[0];   // [128,1152,8]
    const float* W = (const float*)d_in[1];   // [1152,32,8,16]
    float* out = (float*)d_out;               // [128,32,16]

    const size_t slice_elems = (size_t)BATCH * NC * NE;   // 65536

    float* o_sum  = (float*)d_ws;
    void*  s_part = (void*)(o_sum + slice_elems);

    // fp16 plain path: 128 slices x 128 KB = 16.4 MB (+256 KB o_sum)
    int nslice, use_atomic;
    if (ws_size >= slice_elems * sizeof(float) + (size_t)ISPLIT * slice_elems * sizeof(__half)) {
        nslice = ISPLIT; use_atomic = 0;
    } else if (ws_size >= slice_elems * sizeof(float) * (32 + 1)) {
        nslice = 32; use_atomic = 1;
    } else {
        nslice = 8; use_atomic = 1;
    }

    if (use_atomic)
        hipMemsetAsync(s_part, 0, slice_elems * sizeof(float) * nslice, stream);

    for (int it = 0; it < NROUT; ++it) {
        route_iter_kernel<<<dim3(ISPLIT, BATCH / BT), RT_THREADS, 0, stream>>>(
            x, W, o_sum, s_part, it, nslice, use_atomic);
        squash_kernel<<<(BATCH * NC * NE) / (SQ_THREADS * 2), SQ_THREADS, 0, stream>>>(
            s_part, o_sum, out, it, nslice, use_atomic);
    }
}

// Round 10
// 238.140 us; speedup vs baseline: 1.1023x; 1.1023x over previous
//
#include <hip/hip_runtime.h>
#include <hip/hip_fp16.h>
#include <math.h>

// Problem constants (from reference)
#define BATCH 128
#define NI    1152
#define ND    8
#define NC    32
#define NE    16
#define NROUT 3

// Tiling: 256 threads = 32 c x 2 e-halves x 4 batch-groups; NB=4 batches each
// (72-VGPR shape). ISPLIT=128 -> 1024 blocks; with natural VGPR alloc (no
// launch_bounds clamp) LDS=33.8KB permits 4 blocks/CU = 16 waves/CU.
// Partial s stored as fp16 (128 slices x 128 KB = 16.4 MB fits ws).
#define ISPLIT     128
#define ICHUNK     (NI / ISPLIT)    // 9
#define BT         16               // batches per block
#define NB         4                // batches per thread
#define RT_THREADS 256
#define WROW       132              // padded row stride: conflict-free (measured 0)
#define SQ_THREADS 256

template<int CTRL>
__device__ __forceinline__ float dpp_add(float v) {
    int t = __builtin_amdgcn_update_dpp(0, __float_as_int(v), CTRL, 0xF, 0xF, true);
    return v + __int_as_float(t);
}

// Sum over lane bits 0..4 (32 'c' lanes of each eh-half).
__device__ __forceinline__ float sum_over_c(float v) {
    v = dpp_add<0xB1>(v);    // lane ^ 1   quad_perm(1,0,3,2)
    v = dpp_add<0x4E>(v);    // lane ^ 2   quad_perm(2,3,0,1)
    v = dpp_add<0x141>(v);   // lane ^ 4   row_half_mirror
    v = dpp_add<0x140>(v);   // lane ^ 8   row_mirror
    int s = __builtin_amdgcn_ds_swizzle(__float_as_int(v), 0x401F); // lane ^ 16
    return v + __int_as_float(s);
}

// Sum over lane bits 0..2 (8 e-pair lanes) for squash (each thread holds 2 e's).
__device__ __forceinline__ float sum_over_e8(float v) {
    v = dpp_add<0xB1>(v);
    v = dpp_add<0x4E>(v);
    v = dpp_add<0x141>(v);
    return v;
}

// Raw barrier: LDS-ordered (lgkmcnt(0)) but does NOT drain vmcnt — global
// prefetch loads stay in flight across it.
__device__ __forceinline__ void lds_barrier() {
    asm volatile("s_waitcnt lgkmcnt(0)" ::: "memory");
    __builtin_amdgcn_s_barrier();
    __builtin_amdgcn_sched_barrier(0);
}

// ---------------------------------------------------------------------------
// Fused routing iteration. W double-buffered in LDS; x and W software-
// pipelined with counted-vmcnt raw barriers. Softmax over c in-wave (DPP + 1
// swizzle). Partial s written fp16-packed, one slice per ic (atomic fp32
// fallback if ws too small).
// ---------------------------------------------------------------------------
__global__ __launch_bounds__(RT_THREADS, 2)
void route_iter_kernel(const float* __restrict__ x, const float* __restrict__ W,
                       const float* __restrict__ o_sum, void* __restrict__ s_part,
                       int iter, int nslice, int use_atomic)
{
    __shared__ float Ws[2][NC * WROW];   // 2 x 16.9 KB

    const int tid = threadIdx.x;
    const int c   = tid & 31;
    const int eh  = (tid >> 5) & 1;
    const int bp  = __builtin_amdgcn_readfirstlane(tid >> 6);  // wave-uniform
    const int ic  = blockIdx.x;
    const int bt  = blockIdx.y;
    const int i0  = ic * ICHUNK;
    const int b0  = bt * BT + bp * NB;   // 4 consecutive batches per wave
    const int e0  = eh * 8;

    // o_sum[b, c, e0..e0+7] in registers (iter > 0 only)
    float o_reg[NB][8];
    if (iter > 0) {
#pragma unroll
        for (int j = 0; j < NB; ++j) {
            const float4* op = (const float4*)(o_sum + ((size_t)(b0 + j) * NC + c) * NE + e0);
            float4 a = op[0], b = op[1];
            o_reg[j][0] = a.x; o_reg[j][1] = a.y; o_reg[j][2] = a.z; o_reg[j][3] = a.w;
            o_reg[j][4] = b.x; o_reg[j][5] = b.y; o_reg[j][6] = b.z; o_reg[j][7] = b.w;
        }
    }

    float s_acc[NB][8];
#pragma unroll
    for (int j = 0; j < NB; ++j)
#pragma unroll
        for (int e = 0; e < 8; ++e) s_acc[j][e] = 0.f;

    // ---- prologue: x(0) in flight; W(0) staged; W(1) in flight ----
    float4 xn[NB][2];
#pragma unroll
    for (int j = 0; j < NB; ++j) {
        const float4* xp = (const float4*)(x + ((size_t)(b0 + j) * NI + i0) * ND);
        xn[j][0] = xp[0];
        xn[j][1] = xp[1];
    }
    float4 pr[4];
    {
        const float4* src = (const float4*)(W + (size_t)i0 * (NC * ND * NE));
#pragma unroll
        for (int r = 0; r < 4; ++r) pr[r] = src[tid + r * RT_THREADS];
#pragma unroll
        for (int r = 0; r < 4; ++r) {
            int j = tid + r * RT_THREADS;            // float4 chunk 0..1023
            *(float4*)&Ws[0][(j >> 5) * WROW + (j & 31) * 4] = pr[r];
        }
    }
    if (ICHUNK > 1) {
        const float4* src = (const float4*)(W + (size_t)(i0 + 1) * (NC * ND * NE));
#pragma unroll
        for (int r = 0; r < 4; ++r) pr[r] = src[tid + r * RT_THREADS];
    }

    for (int ii = 0; ii < ICHUNK; ++ii) {
        lds_barrier();            // Ws[ii&1] ready; no vmcnt drain

        // xv <- xn (counted vmcnt for x(ii); W prefetch stays in flight)
        float xv[NB][ND];
#pragma unroll
        for (int j = 0; j < NB; ++j) {
            xv[j][0] = xn[j][0].x; xv[j][1] = xn[j][0].y;
            xv[j][2] = xn[j][0].z; xv[j][3] = xn[j][0].w;
            xv[j][4] = xn[j][1].x; xv[j][5] = xn[j][1].y;
            xv[j][6] = xn[j][1].z; xv[j][7] = xn[j][1].w;
        }
        // issue x(ii+1)
        if (ii + 1 < ICHUNK) {
#pragma unroll
            for (int j = 0; j < NB; ++j) {
                const float4* xp = (const float4*)(x + ((size_t)(b0 + j) * NI + (i0 + ii + 1)) * ND);
                xn[j][0] = xp[0];
                xn[j][1] = xp[1];
            }
        }

        // ---- u_hat[b0..b0+3, c, e0..e0+7] ----
        const float* wr = &Ws[ii & 1][c * WROW + e0];
        float uh[NB][8];
#pragma unroll
        for (int j = 0; j < NB; ++j)
#pragma unroll
            for (int e = 0; e < 8; ++e) uh[j][e] = 0.f;

#pragma unroll
        for (int d = 0; d < ND; ++d) {
            float4 wa = *(const float4*)(wr + d * 16);
            float4 wb = *(const float4*)(wr + d * 16 + 4);
#pragma unroll
            for (int j = 0; j < NB; ++j) {
                const float xd = xv[j][d];
                uh[j][0] = fmaf(xd, wa.x, uh[j][0]);
                uh[j][1] = fmaf(xd, wa.y, uh[j][1]);
                uh[j][2] = fmaf(xd, wa.z, uh[j][2]);
                uh[j][3] = fmaf(xd, wa.w, uh[j][3]);
                uh[j][4] = fmaf(xd, wb.x, uh[j][4]);
                uh[j][5] = fmaf(xd, wb.y, uh[j][5]);
                uh[j][6] = fmaf(xd, wb.z, uh[j][6]);
                uh[j][7] = fmaf(xd, wb.w, uh[j][7]);
            }
        }

        // ---- routing weights + s accumulation ----
        if (iter > 0) {
#pragma unroll
            for (int j = 0; j < NB; ++j) {
                float lp = 0.f;
#pragma unroll
                for (int e = 0; e < 8; ++e) lp = fmaf(uh[j][e], o_reg[j][e], lp);
                lp += __shfl_xor(lp, 32);          // combine e-halves -> full logit
                float el = __expf(lp);             // |logit| small; no max-sub
                float den = sum_over_c(el);        // softmax denom over 32 c
                float wgt = el / den;
#pragma unroll
                for (int e = 0; e < 8; ++e) s_acc[j][e] = fmaf(wgt, uh[j][e], s_acc[j][e]);
            }
        } else {
            const float wgt = 1.f / 32.f;
#pragma unroll
            for (int j = 0; j < NB; ++j)
#pragma unroll
                for (int e = 0; e < 8; ++e) s_acc[j][e] = fmaf(wgt, uh[j][e], s_acc[j][e]);
        }

        // ---- write W(ii+1) into the other buffer; issue W(ii+2) ----
        if (ii + 1 < ICHUNK) {
#pragma unroll
            for (int r = 0; r < 4; ++r) {
                int j = tid + r * RT_THREADS;
                *(float4*)&Ws[(ii + 1) & 1][(j >> 5) * WROW + (j & 31) * 4] = pr[r];
            }
            if (ii + 2 < ICHUNK) {
                const float4* src = (const float4*)(W + (size_t)(i0 + ii + 2) * (NC * ND * NE));
#pragma unroll
                for (int r = 0; r < 4; ++r) pr[r] = src[tid + r * RT_THREADS];
            }
        }
    }

    // ---- write partial s ----
    if (!use_atomic) {
        __half* sp = (__half*)s_part;
#pragma unroll
        for (int j = 0; j < NB; ++j) {
            __half* base = sp + (((size_t)ic * BATCH + (b0 + j)) * NC + c) * NE + e0;
            union { __half2 h2[4]; uint4 u; } pk;
#pragma unroll
            for (int q = 0; q < 4; ++q)
                pk.h2[q] = __floats2half2_rn(s_acc[j][2*q], s_acc[j][2*q+1]);
            *(uint4*)base = pk.u;   // 16B aligned: (c*16 + e0)*2 bytes
        }
    } else {
        float* sp = (float*)s_part;
        const int slice = ic & (nslice - 1);
#pragma unroll
        for (int j = 0; j < NB; ++j) {
            float* base = sp + (((size_t)slice * BATCH + (b0 + j)) * NC + c) * NE + e0;
#pragma unroll
            for (int e = 0; e < 8; ++e) atomicAdd(base + e, s_acc[j][e]);
        }
    }
}

// ---------------------------------------------------------------------------
// squash: reduce slices (fp16 plain or fp32 atomic layout), squash, update
// o_sum / write output. Each thread owns an e-pair; e-reduction via DPP over
// lane bits 0..2 (8 pairs).
// ---------------------------------------------------------------------------
__global__ __launch_bounds__(SQ_THREADS)
void squash_kernel(void* __restrict__ s_part, float* __restrict__ o_sum,
                   float* __restrict__ out, int iter, int nslice, int use_atomic)
{
    const int base2 = (blockIdx.x * SQ_THREADS + threadIdx.x) * 2;  // element pair

    float a0 = 0.f, a1 = 0.f;
    if (!use_atomic) {
        const __half* sp = (const __half*)s_part;
        for (int k = 0; k < nslice; ++k) {
            __half2 v = *(const __half2*)(sp + (size_t)k * (BATCH * NC * NE) + base2);
            a0 += __low2float(v);
            a1 += __high2float(v);
        }
    } else {
        float* sp = (float*)s_part;
        for (int k = 0; k < nslice; ++k) {
            float2 v = *(float2*)(sp + (size_t)k * (BATCH * NC * NE) + base2);
            a0 += v.x; a1 += v.y;
            *(float2*)(sp + (size_t)k * (BATCH * NC * NE) + base2) = make_float2(0.f, 0.f);
        }
    }

    float q = sum_over_e8(a0 * a0 + a1 * a1);
    // scale = s2/(1+s2)/sqrt(s2) == sqrt(s2)/(1+s2)
    float scale = sqrtf(q) / (1.f + q);
    float o0 = scale * a0, o1 = scale * a1;

    if (iter == NROUT - 1) {
        *(float2*)(out + base2) = make_float2(o0, o1);
    } else if (iter == 0) {
        *(float2*)(o_sum + base2) = make_float2(o0, o1);
    } else {
        float2 prev = *(float2*)(o_sum + base2);
        *(float2*)(o_sum + base2) = make_float2(prev.x + o0, prev.y + o1);
    }
}

extern "C" void kernel_launch(void* const* d_in, const int* in_sizes, int n_in,
                              void* d_out, int out_size, void* d_ws, size_t ws_size,
                              hipStream_t stream) {
    const float* x = (const float*)d_in[0];   // [128,1152,8]
    const float* W = (const float*)d_in[1];   // [1152,32,8,16]
    float* out = (float*)d_out;               // [128,32,16]

    const size_t slice_elems = (size_t)BATCH * NC * NE;   // 65536

    float* o_sum  = (float*)d_ws;
    void*  s_part = (void*)(o_sum + slice_elems);

    // fp16 plain path: 128 slices x 128 KB = 16.4 MB (+256 KB o_sum)
    int nslice, use_atomic;
    if (ws_size >= slice_elems * sizeof(float) + (size_t)ISPLIT * slice_elems * sizeof(__half)) {
        nslice = ISPLIT; use_atomic = 0;
    } else if (ws_size >= slice_elems * sizeof(float) * (32 + 1)) {
        nslice = 32; use_atomic = 1;
    } else {
        nslice = 8; use_atomic = 1;
    }

    if (use_atomic)
        hipMemsetAsync(s_part, 0, slice_elems * sizeof(float) * nslice, stream);

    for (int it = 0; it < NROUT; ++it) {
        route_iter_kernel<<<dim3(ISPLIT, BATCH / BT), RT_THREADS, 0, stream>>>(
            x, W, o_sum, s_part, it, nslice, use_atomic);
        squash_kernel<<<(BATCH * NC * NE) / (SQ_THREADS * 2), SQ_THREADS, 0, stream>>>(
            s_part, o_sum, out, it, nslice, use_atomic);
    }
}

// Round 11
// 180.838 us; speedup vs baseline: 1.4516x; 1.3169x over previous
//
#include <hip/hip_runtime.h>
#include <math.h>

// Problem constants (from reference)
#define BATCH 128
#define NI    1152
#define ND    8
#define NC    32
#define NE    16
#define NROUT 3

// Tiling: 256 threads = 32 c x 2 e-halves x 4 batch-groups; NB=4 batches each.
// ISPLIT=64 -> fp32 plain-store partials fit ws (proven round 3/6).
#define ISPLIT     64
#define ICHUNK     (NI / ISPLIT)    // 18 (even: unrolled 2x)
#define BT         16
#define NB         4
#define RT_THREADS 256
#define WROW       132              // padded row: measured 0 bank conflicts
#define SQ_THREADS 256
#define TILEF      (NC * ND * NE)   // 4096 floats per W[i] tile

template<int CTRL>
__device__ __forceinline__ float dpp_add(float v) {
    int t = __builtin_amdgcn_update_dpp(0, __float_as_int(v), CTRL, 0xF, 0xF, true);
    return v + __int_as_float(t);
}

// v[i] + v[i^32] for every lane — VALU permlane, not LDS (fallback: shfl)
__device__ __forceinline__ float xor32_sum(float v) {
#if __has_builtin(__builtin_amdgcn_permlane32_swap)
    auto r = __builtin_amdgcn_permlane32_swap(__float_as_int(v), __float_as_int(v), false, false);
    return __int_as_float(r[0]) + __int_as_float(r[1]);
#else
    return v + __shfl_xor(v, 32);
#endif
}
// v[i] + v[i^16] — VALU permlane (fallback: ds_swizzle)
__device__ __forceinline__ float xor16_sum(float v) {
#if __has_builtin(__builtin_amdgcn_permlane16_swap)
    auto r = __builtin_amdgcn_permlane16_swap(__float_as_int(v), __float_as_int(v), false, false);
    return __int_as_float(r[0]) + __int_as_float(r[1]);
#else
    int s = __builtin_amdgcn_ds_swizzle(__float_as_int(v), 0x401F);
    return v + __int_as_float(s);
#endif
}

// LDS-ordered barrier that does NOT drain vmcnt: vector-memory prefetch
// survives it. (SMEM can't — which is why x must be on the vector path.)
__device__ __forceinline__ void lds_barrier() {
    asm volatile("s_waitcnt lgkmcnt(0)" ::: "memory");
    __builtin_amdgcn_s_barrier();
    __builtin_amdgcn_sched_barrier(0);
}

// ---------------------------------------------------------------------------
// Fused routing iteration. W double-buffered in LDS; x and W pipelined via
// VECTOR loads (wave-id laundered through v_mov so the compiler cannot
// scalarize x to s_load — s_load would drain at every lgkmcnt(0) barrier).
// Softmax over c fully VALU (DPP + permlane swaps). fp32 partial s, one
// slice per ic (atomic fallback).
// ---------------------------------------------------------------------------
__global__ __launch_bounds__(RT_THREADS, 2)
void route_iter_kernel(const float* __restrict__ x, const float* __restrict__ W,
                       const float* __restrict__ o_sum, float* __restrict__ s_part,
                       int iter, int nslice, int use_atomic)
{
    __shared__ float Ws[2][NC * WROW];   // 2 x 16.9 KB

    const int tid = threadIdx.x;
    const int c   = tid & 31;
    const int eh  = (tid >> 5) & 1;
    int wid;   // laundered wave id: opaque VGPR -> x addresses stay divergent
    asm("v_mov_b32 %0, %1" : "=v"(wid) : "v"(tid >> 6));
    const int ic  = blockIdx.x;
    const int bt  = blockIdx.y;
    const int i0  = ic * ICHUNK;
    const int b0  = bt * BT + wid * NB;
    const int e0  = eh * 8;
    const int lane_off = c * WROW + e0;

    int lwoff[4];
#pragma unroll
    for (int r = 0; r < 4; ++r) {
        int jj = tid + r * RT_THREADS;
        lwoff[r] = (jj >> 5) * WROW + (jj & 31) * 4;
    }

    // o_sum[b, c, e0..e0+7] in registers (iter > 0 only)
    float o_reg[NB][8];
    if (iter > 0) {
#pragma unroll
        for (int j = 0; j < NB; ++j) {
            const float4* op = (const float4*)(o_sum + ((size_t)(b0 + j) * NC + c) * NE + e0);
            float4 a = op[0], b = op[1];
            o_reg[j][0] = a.x; o_reg[j][1] = a.y; o_reg[j][2] = a.z; o_reg[j][3] = a.w;
            o_reg[j][4] = b.x; o_reg[j][5] = b.y; o_reg[j][6] = b.z; o_reg[j][7] = b.w;
        }
    }

    float s_acc[NB][8];
#pragma unroll
    for (int j = 0; j < NB; ++j)
#pragma unroll
        for (int e = 0; e < 8; ++e) s_acc[j][e] = 0.f;

    // ---- prologue: x(0) in flight (vector); W(0) staged; W(1) in flight ----
    const float* xp[NB];
    float4 xnA[NB][2], xnB[NB][2];
#pragma unroll
    for (int j = 0; j < NB; ++j) {
        xp[j] = x + ((size_t)(b0 + j) * NI + i0) * ND;
        xnA[j][0] = *(const float4*)xp[j];
        xnA[j][1] = *(const float4*)(xp[j] + 4);
    }

    const float4* wp = (const float4*)(W + (size_t)i0 * TILEF);
    float4 pr[4];
#pragma unroll
    for (int r = 0; r < 4; ++r) pr[r] = wp[tid + r * RT_THREADS];
    wp += 1024;

    float* const buf0 = &Ws[0][0];
    float* const buf1 = &Ws[1][0];
#pragma unroll
    for (int r = 0; r < 4; ++r) *(float4*)(buf0 + lwoff[r]) = pr[r];
    // issue W(1)
#pragma unroll
    for (int r = 0; r < 4; ++r) pr[r] = wp[tid + r * RT_THREADS];
    wp += 1024;

    auto body = [&](const float4 (&XC)[NB][2], float4 (&XN)[NB][2],
                    const float* BR, float* BW, int II) {
        lds_barrier();            // Ws ready; vmcnt NOT drained

        // issue x(II+1) into the other x buffer (different vars: no WAR)
        if (II + 1 < ICHUNK) {
#pragma unroll
            for (int j = 0; j < NB; ++j) {
                xp[j] += ND;
                XN[j][0] = *(const float4*)xp[j];
                XN[j][1] = *(const float4*)(xp[j] + 4);
            }
        }

        // ---- u_hat ----
        const float* wr = BR + lane_off;
        float uh[NB][8];
#pragma unroll
        for (int j = 0; j < NB; ++j)
#pragma unroll
            for (int e = 0; e < 8; ++e) uh[j][e] = 0.f;

#pragma unroll
        for (int d = 0; d < ND; ++d) {
            float4 wa = *(const float4*)(wr + d * 16);
            float4 wb = *(const float4*)(wr + d * 16 + 4);
#pragma unroll
            for (int j = 0; j < NB; ++j) {
                const float4 xh = (d < 4) ? XC[j][0] : XC[j][1];
                const int dk = d & 3;
                const float xd = dk == 0 ? xh.x : dk == 1 ? xh.y : dk == 2 ? xh.z : xh.w;
                uh[j][0] = fmaf(xd, wa.x, uh[j][0]);
                uh[j][1] = fmaf(xd, wa.y, uh[j][1]);
                uh[j][2] = fmaf(xd, wa.z, uh[j][2]);
                uh[j][3] = fmaf(xd, wa.w, uh[j][3]);
                uh[j][4] = fmaf(xd, wb.x, uh[j][4]);
                uh[j][5] = fmaf(xd, wb.y, uh[j][5]);
                uh[j][6] = fmaf(xd, wb.z, uh[j][6]);
                uh[j][7] = fmaf(xd, wb.w, uh[j][7]);
            }
        }

        // ---- routing weights + s accumulation (all-VALU reductions) ----
        if (iter > 0) {
#pragma unroll
            for (int j = 0; j < NB; ++j) {
                float lp = 0.f;
#pragma unroll
                for (int e = 0; e < 8; ++e) lp = fmaf(uh[j][e], o_reg[j][e], lp);
                lp = xor32_sum(lp);                 // combine e-halves (VALU)
                float el = __expf(lp);              // |logit| small; no max-sub
                float v = dpp_add<0x140>(dpp_add<0x141>(
                          dpp_add<0x4E>(dpp_add<0xB1>(el))));
                float den = xor16_sum(v);           // softmax denom over 32 c
                float wgt = el * __builtin_amdgcn_rcpf(den);
#pragma unroll
                for (int e = 0; e < 8; ++e) s_acc[j][e] = fmaf(wgt, uh[j][e], s_acc[j][e]);
            }
        } else {
            const float wgt = 1.f / 32.f;
#pragma unroll
            for (int j = 0; j < NB; ++j)
#pragma unroll
                for (int e = 0; e < 8; ++e) s_acc[j][e] = fmaf(wgt, uh[j][e], s_acc[j][e]);
        }

        // ---- write W(II+1) into the other buffer; issue W(II+2) ----
        if (II + 1 < ICHUNK) {
#pragma unroll
            for (int r = 0; r < 4; ++r) *(float4*)(BW + lwoff[r]) = pr[r];
            if (II + 2 < ICHUNK) {
#pragma unroll
                for (int r = 0; r < 4; ++r) pr[r] = wp[tid + r * RT_THREADS];
                wp += 1024;
            }
        }
    };

    for (int r2 = 0; r2 < ICHUNK / 2; ++r2) {
        body(xnA, xnB, buf0, buf1, 2 * r2);
        body(xnB, xnA, buf1, buf0, 2 * r2 + 1);
    }

    // ---- write partial s ----
    const int slice = use_atomic ? (ic & (nslice - 1)) : ic;
#pragma unroll
    for (int j = 0; j < NB; ++j) {
        float* base = s_part + (((size_t)slice * BATCH + (b0 + j)) * NC + c) * NE + e0;
        if (use_atomic) {
#pragma unroll
            for (int e = 0; e < 8; ++e) atomicAdd(base + e, s_acc[j][e]);
        } else {
            *(float4*)(base)     = make_float4(s_acc[j][0], s_acc[j][1], s_acc[j][2], s_acc[j][3]);
            *(float4*)(base + 4) = make_float4(s_acc[j][4], s_acc[j][5], s_acc[j][6], s_acc[j][7]);
        }
    }
}

// ---------------------------------------------------------------------------
// squash: reduce slices (float4 per thread), squash, update o_sum / output.
// (b,c) spans 4 adjacent lanes -> e-reduction via 2 DPP adds.
// ---------------------------------------------------------------------------
__global__ __launch_bounds__(SQ_THREADS)
void squash_kernel(float* __restrict__ s_part, float* __restrict__ o_sum,
                   float* __restrict__ out, int iter, int nslice, int zero_after)
{
    const int idx4 = blockIdx.x * SQ_THREADS + threadIdx.x;   // float4 index
    float4* sp4 = (float4*)s_part;

    float ax = 0.f, ay = 0.f, az = 0.f, aw = 0.f;
#pragma unroll 8
    for (int k = 0; k < nslice; ++k) {
        float4* p = sp4 + (size_t)k * (BATCH * NC * NE / 4) + idx4;
        float4 v = *p;
        ax += v.x; ay += v.y; az += v.z; aw += v.w;
        if (zero_after) *p = make_float4(0.f, 0.f, 0.f, 0.f);
    }

    float q = ax * ax + ay * ay + az * az + aw * aw;
    q = dpp_add<0xB1>(q);   // lane ^ 1
    q = dpp_add<0x4E>(q);   // lane ^ 2  -> full 16-e sum of squares
    // scale = s2/(1+s2)/sqrt(s2) == sqrt(s2)/(1+s2)
    float scale = sqrtf(q) / (1.f + q);
    float4 o = make_float4(scale * ax, scale * ay, scale * az, scale * aw);

    if (iter == NROUT - 1) {
        ((float4*)out)[idx4] = o;
    } else if (iter == 0) {
        ((float4*)o_sum)[idx4] = o;
    } else {
        float4 p = ((float4*)o_sum)[idx4];
        ((float4*)o_sum)[idx4] = make_float4(p.x + o.x, p.y + o.y, p.z + o.z, p.w + o.w);
    }
}

extern "C" void kernel_launch(void* const* d_in, const int* in_sizes, int n_in,
                              void* d_out, int out_size, void* d_ws, size_t ws_size,
                              hipStream_t stream) {
    const float* x = (const float*)d_in[0];   // [128,1152,8]
    const float* W = (const float*)d_in[1];   // [1152,32,8,16]
    float* out = (float*)d_out;               // [128,32,16]

    const size_t slice_elems = (size_t)BATCH * NC * NE;   // 65536
    const size_t slice_bytes = slice_elems * sizeof(float);

    float* o_sum  = (float*)d_ws;
    float* s_part = o_sum + slice_elems;

    int nslice, use_atomic;
    if (ws_size >= slice_bytes * (ISPLIT + 1))  { nslice = ISPLIT; use_atomic = 0; }
    else if (ws_size >= slice_bytes * (32 + 1)) { nslice = 32; use_atomic = 1; }
    else if (ws_size >= slice_bytes * (8 + 1))  { nslice = 8;  use_atomic = 1; }
    else                                        { nslice = 1;  use_atomic = 1; }

    if (use_atomic)
        hipMemsetAsync(s_part, 0, slice_bytes * nslice, stream);

    for (int it = 0; it < NROUT; ++it) {
        route_iter_kernel<<<dim3(ISPLIT, BATCH / BT), RT_THREADS, 0, stream>>>(
            x, W, o_sum, s_part, it, nslice, use_atomic);
        squash_kernel<<<(BATCH * NC * NE / 4) / SQ_THREADS, SQ_THREADS, 0, stream>>>(
            s_part, o_sum, out, it, nslice, use_atomic);
    }
}

// Round 12
// 131.808 us; speedup vs baseline: 1.9916x; 1.3720x over previous
//
#include <hip/hip_runtime.h>
#include <hip/hip_fp16.h>
#include <math.h>

// Problem constants (from reference)
#define BATCH 128
#define NI    1152
#define ND    8
#define NC    32
#define NE    16
#define NROUT 3

// Persistent-W structure: stage ICHUNK=9 W tiles (152 KB) in LDS ONCE,
// then a completely barrier-free compute loop (W is read-only after stage).
// 256 threads = 32 c x 2 eh x 4 bp; NB=4 batches/thread.
// ISPLIT=128 -> fp16 partials: 128 x 128KB + 256KB o_sum = 16.64 MB (= r3's
// proven-fit ws footprint).
#define ISPLIT     128
#define ICHUNK     (NI / ISPLIT)    // 9
#define BT         16
#define NB         4
#define RT_THREADS 256
#define WROW       132              // padded row: measured 0 bank conflicts
#define TLDS       (NC * WROW)      // 4224 floats per staged tile
#define TILEF      (NC * ND * NE)   // 4096 floats per W[i] tile in global
#define SQ_THREADS 256

template<int CTRL>
__device__ __forceinline__ float dpp_add(float v) {
    int t = __builtin_amdgcn_update_dpp(0, __float_as_int(v), CTRL, 0xF, 0xF, true);
    return v + __int_as_float(t);
}

// v[i] + v[i^32] — VALU permlane (fallback: shfl)
__device__ __forceinline__ float xor32_sum(float v) {
#if __has_builtin(__builtin_amdgcn_permlane32_swap)
    auto r = __builtin_amdgcn_permlane32_swap(__float_as_int(v), __float_as_int(v), false, false);
    return __int_as_float(r[0]) + __int_as_float(r[1]);
#else
    return v + __shfl_xor(v, 32);
#endif
}
// v[i] + v[i^16] — VALU permlane (fallback: ds_swizzle)
__device__ __forceinline__ float xor16_sum(float v) {
#if __has_builtin(__builtin_amdgcn_permlane16_swap)
    auto r = __builtin_amdgcn_permlane16_swap(__float_as_int(v), __float_as_int(v), false, false);
    return __int_as_float(r[0]) + __int_as_float(r[1]);
#else
    int s = __builtin_amdgcn_ds_swizzle(__float_as_int(v), 0x401F);
    return v + __int_as_float(s);
#endif
}

// Sum over lane bits 0..2 (8 e-pair lanes) for squash.
__device__ __forceinline__ float sum_over_e8(float v) {
    v = dpp_add<0xB1>(v);
    v = dpp_add<0x4E>(v);
    v = dpp_add<0x141>(v);
    return v;
}

// ---------------------------------------------------------------------------
// Fused routing iteration, barrier-free main loop.
//   1. stage 9 W tiles to LDS (coalesced, reg round-trip), ONE __syncthreads
//   2. for ii in 0..8 (fully unrolled): compute u_hat / softmax / s_acc with
//      NO barriers — waves run independently; ds_reads pipeline freely.
// Partial s written fp16-packed per ic slice (atomic fp32 fallback).
// ---------------------------------------------------------------------------
__global__ __launch_bounds__(RT_THREADS)
void route_iter_kernel(const float* __restrict__ x, const float* __restrict__ W,
                       const float* __restrict__ o_sum, void* __restrict__ s_part,
                       int iter, int nslice, int use_atomic)
{
    __shared__ float Ws[ICHUNK * TLDS];   // 9 x 16.9 KB = 152 KB

    const int tid = threadIdx.x;
    const int c   = tid & 31;
    const int eh  = (tid >> 5) & 1;
    int wid;   // laundered wave id -> x addresses stay on the vector path
    asm("v_mov_b32 %0, %1" : "=v"(wid) : "v"(tid >> 6));
    const int ic  = blockIdx.x;
    const int bt  = blockIdx.y;
    const int i0  = ic * ICHUNK;
    const int b0  = bt * BT + wid * NB;
    const int e0  = eh * 8;
    const int lane_off = c * WROW + e0;

    // ---- stage all 9 tiles (36 float4 per thread), one barrier ----
    {
        const float4* wsrc = (const float4*)(W + (size_t)i0 * TILEF);
        float4 tmp[36];
#pragma unroll
        for (int r = 0; r < 36; ++r) tmp[r] = wsrc[tid + r * RT_THREADS];
#pragma unroll
        for (int r = 0; r < 36; ++r) {
            int g = tid + r * RT_THREADS;          // float4 chunk 0..9215
            int t = g >> 10;                       // tile 0..8
            int j = g & 1023;                      // chunk within tile
            *(float4*)&Ws[t * TLDS + (j >> 5) * WROW + (j & 31) * 4] = tmp[r];
        }
    }

    // o_sum[b, c, e0..e0+7] in registers (iter > 0 only)
    float o_reg[NB][8];
    if (iter > 0) {
#pragma unroll
        for (int j = 0; j < NB; ++j) {
            const float4* op = (const float4*)(o_sum + ((size_t)(b0 + j) * NC + c) * NE + e0);
            float4 a = op[0], b = op[1];
            o_reg[j][0] = a.x; o_reg[j][1] = a.y; o_reg[j][2] = a.z; o_reg[j][3] = a.w;
            o_reg[j][4] = b.x; o_reg[j][5] = b.y; o_reg[j][6] = b.z; o_reg[j][7] = b.w;
        }
    }

    float s_acc[NB][8];
#pragma unroll
    for (int j = 0; j < NB; ++j)
#pragma unroll
        for (int e = 0; e < 8; ++e) s_acc[j][e] = 0.f;

    // x(0) prefetch (vector loads; survive everything)
    const float* xp[NB];
    float4 xnA[NB][2], xnB[NB][2];
#pragma unroll
    for (int j = 0; j < NB; ++j) {
        xp[j] = x + ((size_t)(b0 + j) * NI + i0) * ND;
        xnA[j][0] = *(const float4*)xp[j];
        xnA[j][1] = *(const float4*)(xp[j] + 4);
    }

    __syncthreads();   // the ONLY barrier: staged W visible to all waves

    auto body = [&](const float4 (&XC)[NB][2], float4 (&XN)[NB][2], int II) {
        // issue x(II+1) into the other x register buffer
        if (II + 1 < ICHUNK) {
#pragma unroll
            for (int j = 0; j < NB; ++j) {
                xp[j] += ND;
                XN[j][0] = *(const float4*)xp[j];
                XN[j][1] = *(const float4*)(xp[j] + 4);
            }
        }

        // ---- u_hat from resident LDS tile II ----
        const float* wr = &Ws[II * TLDS] + lane_off;
        float uh[NB][8];
#pragma unroll
        for (int j = 0; j < NB; ++j)
#pragma unroll
            for (int e = 0; e < 8; ++e) uh[j][e] = 0.f;

#pragma unroll
        for (int d = 0; d < ND; ++d) {
            float4 wa = *(const float4*)(wr + d * 16);
            float4 wb = *(const float4*)(wr + d * 16 + 4);
#pragma unroll
            for (int j = 0; j < NB; ++j) {
                const float4 xh = (d < 4) ? XC[j][0] : XC[j][1];
                const int dk = d & 3;
                const float xd = dk == 0 ? xh.x : dk == 1 ? xh.y : dk == 2 ? xh.z : xh.w;
                uh[j][0] = fmaf(xd, wa.x, uh[j][0]);
                uh[j][1] = fmaf(xd, wa.y, uh[j][1]);
                uh[j][2] = fmaf(xd, wa.z, uh[j][2]);
                uh[j][3] = fmaf(xd, wa.w, uh[j][3]);
                uh[j][4] = fmaf(xd, wb.x, uh[j][4]);
                uh[j][5] = fmaf(xd, wb.y, uh[j][5]);
                uh[j][6] = fmaf(xd, wb.z, uh[j][6]);
                uh[j][7] = fmaf(xd, wb.w, uh[j][7]);
            }
        }

        // ---- routing weights + s accumulation (all-VALU reductions) ----
        if (iter > 0) {
#pragma unroll
            for (int j = 0; j < NB; ++j) {
                float lp = 0.f;
#pragma unroll
                for (int e = 0; e < 8; ++e) lp = fmaf(uh[j][e], o_reg[j][e], lp);
                lp = xor32_sum(lp);                 // combine e-halves
                float el = __expf(lp);              // |logit| small; no max-sub
                float v = dpp_add<0x140>(dpp_add<0x141>(
                          dpp_add<0x4E>(dpp_add<0xB1>(el))));
                float den = xor16_sum(v);           // softmax denom over 32 c
                float wgt = el * __builtin_amdgcn_rcpf(den);
#pragma unroll
                for (int e = 0; e < 8; ++e) s_acc[j][e] = fmaf(wgt, uh[j][e], s_acc[j][e]);
            }
        } else {
            const float wgt = 1.f / 32.f;
#pragma unroll
            for (int j = 0; j < NB; ++j)
#pragma unroll
                for (int e = 0; e < 8; ++e) s_acc[j][e] = fmaf(wgt, uh[j][e], s_acc[j][e]);
        }
    };

    // 9 unrolled, barrier-free iterations (A/B x-buffer alternation)
    body(xnA, xnB, 0);
    body(xnB, xnA, 1);
    body(xnA, xnB, 2);
    body(xnB, xnA, 3);
    body(xnA, xnB, 4);
    body(xnB, xnA, 5);
    body(xnA, xnB, 6);
    body(xnB, xnA, 7);
    body(xnA, xnB, 8);

    // ---- write partial s ----
    if (!use_atomic) {
        __half* sp = (__half*)s_part;
#pragma unroll
        for (int j = 0; j < NB; ++j) {
            __half* base = sp + (((size_t)ic * BATCH + (b0 + j)) * NC + c) * NE + e0;
            union { __half2 h2[4]; uint4 u; } pk;
#pragma unroll
            for (int q = 0; q < 4; ++q)
                pk.h2[q] = __floats2half2_rn(s_acc[j][2*q], s_acc[j][2*q+1]);
            *(uint4*)base = pk.u;
        }
    } else {
        float* sp = (float*)s_part;
        const int slice = ic & (nslice - 1);
#pragma unroll
        for (int j = 0; j < NB; ++j) {
            float* base = sp + (((size_t)slice * BATCH + (b0 + j)) * NC + c) * NE + e0;
#pragma unroll
            for (int e = 0; e < 8; ++e) atomicAdd(base + e, s_acc[j][e]);
        }
    }
}

// ---------------------------------------------------------------------------
// squash: reduce slices (fp16 plain or fp32 atomic layout), squash, update
// o_sum / write output. Each thread owns an e-pair; DPP e-reduction.
// ---------------------------------------------------------------------------
__global__ __launch_bounds__(SQ_THREADS)
void squash_kernel(void* __restrict__ s_part, float* __restrict__ o_sum,
                   float* __restrict__ out, int iter, int nslice, int use_atomic)
{
    const int base2 = (blockIdx.x * SQ_THREADS + threadIdx.x) * 2;  // element pair

    float a0 = 0.f, a1 = 0.f;
    if (!use_atomic) {
        const __half* sp = (const __half*)s_part;
#pragma unroll 8
        for (int k = 0; k < nslice; ++k) {
            __half2 v = *(const __half2*)(sp + (size_t)k * (BATCH * NC * NE) + base2);
            a0 += __low2float(v);
            a1 += __high2float(v);
        }
    } else {
        float* sp = (float*)s_part;
        for (int k = 0; k < nslice; ++k) {
            float2 v = *(float2*)(sp + (size_t)k * (BATCH * NC * NE) + base2);
            a0 += v.x; a1 += v.y;
            *(float2*)(sp + (size_t)k * (BATCH * NC * NE) + base2) = make_float2(0.f, 0.f);
        }
    }

    float q = sum_over_e8(a0 * a0 + a1 * a1);
    // scale = s2/(1+s2)/sqrt(s2) == sqrt(s2)/(1+s2)
    float scale = sqrtf(q) / (1.f + q);
    float o0 = scale * a0, o1 = scale * a1;

    if (iter == NROUT - 1) {
        *(float2*)(out + base2) = make_float2(o0, o1);
    } else if (iter == 0) {
        *(float2*)(o_sum + base2) = make_float2(o0, o1);
    } else {
        float2 prev = *(float2*)(o_sum + base2);
        *(float2*)(o_sum + base2) = make_float2(prev.x + o0, prev.y + o1);
    }
}

extern "C" void kernel_launch(void* const* d_in, const int* in_sizes, int n_in,
                              void* d_out, int out_size, void* d_ws, size_t ws_size,
                              hipStream_t stream) {
    const float* x = (const float*)d_in[0];   // [128,1152,8]
    const float* W = (const float*)d_in[1];   // [1152,32,8,16]
    float* out = (float*)d_out;               // [128,32,16]

    const size_t slice_elems = (size_t)BATCH * NC * NE;   // 65536

    float* o_sum  = (float*)d_ws;
    void*  s_part = (void*)(o_sum + slice_elems);

    // fp16 plain path: 128 slices x 128 KB + 256 KB o_sum = 16.64 MB
    int nslice, use_atomic;
    if (ws_size >= slice_elems * sizeof(float) + (size_t)ISPLIT * slice_elems * sizeof(__half)) {
        nslice = ISPLIT; use_atomic = 0;
    } else if (ws_size >= slice_elems * sizeof(float) * (32 + 1)) {
        nslice = 32; use_atomic = 1;
    } else {
        nslice = 8; use_atomic = 1;
    }

    if (use_atomic)
        hipMemsetAsync(s_part, 0, slice_elems * sizeof(float) * nslice, stream);

    for (int it = 0; it < NROUT; ++it) {
        route_iter_kernel<<<dim3(ISPLIT, BATCH / BT), RT_THREADS, 0, stream>>>(
            x, W, o_sum, s_part, it, nslice, use_atomic);
        squash_kernel<<<(BATCH * NC * NE) / (SQ_THREADS * 2), SQ_THREADS, 0, stream>>>(
            s_part, o_sum, out, it, nslice, use_atomic);
    }
}

// Round 14
// 107.934 us; speedup vs baseline: 2.4321x; 1.2212x over previous
//
#include <hip/hip_runtime.h>
#include <hip/hip_fp16.h>
#include <math.h>

// Problem constants (from reference)
#define BATCH 128
#define NI    1152
#define ND    8
#define NC    32
#define NE    16
#define NROUT 3

// Persistent-W structure, fp16 edition: stage ICHUNK=9 W tiles as half2
// d-pairs in transposed [c][e][dp] layout (76.5 KB -> 2 blocks/CU), then a
// barrier-free compute loop using v_dot2_f32_f16.
// 256 threads = 32 c x 2 eh x 4 bp; NB=4 batches/thread.
// ISPLIT=128 -> fp16 partials (16.64 MB, proven fit).
#define ISPLIT     128
#define ICHUNK     (NI / ISPLIT)    // 9
#define BT         16
#define NB         4
#define RT_THREADS 256
#define CROW       68               // words per c row: 16e x 4dp + 4 pad (68%32=4)
#define TLDSW      (NC * CROW)      // 2176 words per staged tile
#define TILEF      (NC * ND * NE)   // 4096 floats per W[i] tile in global
#define SQ_THREADS 256

typedef _Float16 h2 __attribute__((ext_vector_type(2)));
typedef unsigned int uint;

// cvt_pkrtz returns a __fp16 vector type; bit-cast to h2 (_Float16 vector).
__device__ __forceinline__ h2 cvt_pk(float a, float b) {
    auto r = __builtin_amdgcn_cvt_pkrtz(a, b);
    union { decltype(r) i; h2 o; } u; u.i = r; return u.o;
}
__device__ __forceinline__ uint h2u(h2 v) { union { h2 h; uint u; } x; x.h = v; return x.u; }
__device__ __forceinline__ h2 u2h(uint v) { union { uint u; h2 h; } x; x.u = v; return x.h; }

#if __has_builtin(__builtin_amdgcn_fdot2)
#define FDOT2(a, b, c) __builtin_amdgcn_fdot2((a), (b), (c), false)
#else
__device__ __forceinline__ float FDOT2(h2 a, h2 b, float c) {
    return c + (float)a.x * (float)b.x + (float)a.y * (float)b.y;
}
#endif

template<int CTRL>
__device__ __forceinline__ float dpp_add(float v) {
    int t = __builtin_amdgcn_update_dpp(0, __float_as_int(v), CTRL, 0xF, 0xF, true);
    return v + __int_as_float(t);
}

// v[i] + v[i^32] — VALU permlane (fallback: shfl)
__device__ __forceinline__ float xor32_sum(float v) {
#if __has_builtin(__builtin_amdgcn_permlane32_swap)
    auto r = __builtin_amdgcn_permlane32_swap(__float_as_int(v), __float_as_int(v), false, false);
    return __int_as_float(r[0]) + __int_as_float(r[1]);
#else
    return v + __shfl_xor(v, 32);
#endif
}
// v[i] + v[i^16] — VALU permlane (fallback: ds_swizzle)
__device__ __forceinline__ float xor16_sum(float v) {
#if __has_builtin(__builtin_amdgcn_permlane16_swap)
    auto r = __builtin_amdgcn_permlane16_swap(__float_as_int(v), __float_as_int(v), false, false);
    return __int_as_float(r[0]) + __int_as_float(r[1]);
#else
    int s = __builtin_amdgcn_ds_swizzle(__float_as_int(v), 0x401F);
    return v + __int_as_float(s);
#endif
}

// Sum over lane bits 0..2 (8 e-pair lanes) for squash.
__device__ __forceinline__ float sum_over_e8(float v) {
    v = dpp_add<0xB1>(v);
    v = dpp_add<0x4E>(v);
    v = dpp_add<0x141>(v);
    return v;
}

// ---------------------------------------------------------------------------
// Fused routing iteration, barrier-free main loop, fp16 W tiles.
//   1. stage 9 W tiles to LDS as half2 d-pairs, transposed to [c][e][dp]
//      (one __syncthreads total)
//   2. 9 unrolled iterations: 8 ds_read_b128 + 128 v_dot2 per thread, no
//      barriers — waves run independently.
// Partial s written fp16-packed per ic slice (atomic fp32 fallback).
// ---------------------------------------------------------------------------
__global__ __launch_bounds__(RT_THREADS)
void route_iter_kernel(const float* __restrict__ x, const float* __restrict__ W,
                       const float* __restrict__ o_sum, void* __restrict__ s_part,
                       int iter, int nslice, int use_atomic)
{
    __shared__ uint Wh[ICHUNK * TLDSW];   // 9 x 8.5 KB = 76.5 KB -> 2 blocks/CU

    const int tid = threadIdx.x;
    const int c   = tid & 31;
    const int eh  = (tid >> 5) & 1;
    int wid;   // laundered wave id -> x addresses stay on the vector path
    asm("v_mov_b32 %0, %1" : "=v"(wid) : "v"(tid >> 6));
    const int ic  = blockIdx.x;
    const int bt  = blockIdx.y;
    const int i0  = ic * ICHUNK;
    const int b0  = bt * BT + wid * NB;
    const int e0  = eh * 8;

    // ---- stage 9 tiles: fp32 -> half2 d-pairs, [c][e][dp] layout ----
    {
        const float4* wsrc = (const float4*)(W + (size_t)i0 * TILEF);
        const int p0 = tid;            // pair ids p0, p0+256 (512 pairs/tile)
#pragma unroll
        for (int t = 0; t < ICHUNK; ++t) {
            float4 fa[2], fb[2];
#pragma unroll
            for (int r = 0; r < 2; ++r) {
                int p  = p0 + r * RT_THREADS;
                int cc = p >> 4, q = p & 15;
                int dp = q >> 2, e4 = q & 3;
                int base = t * 1024 + cc * 32 + dp * 8 + e4;
                fa[r] = wsrc[base];        // d = 2*dp
                fb[r] = wsrc[base + 4];    // d = 2*dp+1
            }
#pragma unroll
            for (int r = 0; r < 2; ++r) {
                int p  = p0 + r * RT_THREADS;
                int cc = p >> 4, q = p & 15;
                int dp = q >> 2, e4 = q & 3;
                uint* wb = &Wh[t * TLDSW + cc * CROW + e4 * 16 + dp];
                wb[0]  = h2u(cvt_pk(fa[r].x, fb[r].x));
                wb[4]  = h2u(cvt_pk(fa[r].y, fb[r].y));
                wb[8]  = h2u(cvt_pk(fa[r].z, fb[r].z));
                wb[12] = h2u(cvt_pk(fa[r].w, fb[r].w));
            }
        }
    }

    // o_sum[b, c, e0..e0+7] in registers (iter > 0 only)
    float o_reg[NB][8];
    if (iter > 0) {
#pragma unroll
        for (int j = 0; j < NB; ++j) {
            const float4* op = (const float4*)(o_sum + ((size_t)(b0 + j) * NC + c) * NE + e0);
            float4 a = op[0], b = op[1];
            o_reg[j][0] = a.x; o_reg[j][1] = a.y; o_reg[j][2] = a.z; o_reg[j][3] = a.w;
            o_reg[j][4] = b.x; o_reg[j][5] = b.y; o_reg[j][6] = b.z; o_reg[j][7] = b.w;
        }
    }

    float s_acc[NB][8];
#pragma unroll
    for (int j = 0; j < NB; ++j)
#pragma unroll
        for (int e = 0; e < 8; ++e) s_acc[j][e] = 0.f;

    // x(0) prefetch (vector loads)
    const float* xp[NB];
    float4 xnA[NB][2], xnB[NB][2];
#pragma unroll
    for (int j = 0; j < NB; ++j) {
        xp[j] = x + ((size_t)(b0 + j) * NI + i0) * ND;
        xnA[j][0] = *(const float4*)xp[j];
        xnA[j][1] = *(const float4*)(xp[j] + 4);
    }

    __syncthreads();   // the ONLY barrier: staged W visible to all waves

    const uint* wbase = &Wh[c * CROW + e0 * 4];

    auto body = [&](const float4 (&XC)[NB][2], float4 (&XN)[NB][2], int II) {
        // issue x(II+1) into the other x register buffer
        if (II + 1 < ICHUNK) {
#pragma unroll
            for (int j = 0; j < NB; ++j) {
                xp[j] += ND;
                XN[j][0] = *(const float4*)xp[j];
                XN[j][1] = *(const float4*)(xp[j] + 4);
            }
        }

        // x -> half2 d-pairs
        h2 xq[NB][4];
#pragma unroll
        for (int j = 0; j < NB; ++j) {
            xq[j][0] = cvt_pk(XC[j][0].x, XC[j][0].y);
            xq[j][1] = cvt_pk(XC[j][0].z, XC[j][0].w);
            xq[j][2] = cvt_pk(XC[j][1].x, XC[j][1].y);
            xq[j][3] = cvt_pk(XC[j][1].z, XC[j][1].w);
        }

        // ---- u_hat from resident LDS tile II (8 b128, 128 dot2) ----
        const uint* wr = wbase + II * TLDSW;
        float uh[NB][8];
#pragma unroll
        for (int j = 0; j < NB; ++j)
#pragma unroll
            for (int e = 0; e < 8; ++e) uh[j][e] = 0.f;

#pragma unroll
        for (int er = 0; er < 8; ++er) {
            uint4 wv = *(const uint4*)(wr + er * 4);
            h2 w0 = u2h(wv.x), w1 = u2h(wv.y), w2 = u2h(wv.z), w3 = u2h(wv.w);
#pragma unroll
            for (int j = 0; j < NB; ++j) {
                float acc = uh[j][er];
                acc = FDOT2(xq[j][0], w0, acc);
                acc = FDOT2(xq[j][1], w1, acc);
                acc = FDOT2(xq[j][2], w2, acc);
                acc = FDOT2(xq[j][3], w3, acc);
                uh[j][er] = acc;
            }
        }

        // ---- routing weights + s accumulation (all-VALU reductions) ----
        if (iter > 0) {
#pragma unroll
            for (int j = 0; j < NB; ++j) {
                float lp = 0.f;
#pragma unroll
                for (int e = 0; e < 8; ++e) lp = fmaf(uh[j][e], o_reg[j][e], lp);
                lp = xor32_sum(lp);                 // combine e-halves
                float el = __expf(lp);              // |logit| small; no max-sub
                float v = dpp_add<0x140>(dpp_add<0x141>(
                          dpp_add<0x4E>(dpp_add<0xB1>(el))));
                float den = xor16_sum(v);           // softmax denom over 32 c
                float wgt = el * __builtin_amdgcn_rcpf(den);
#pragma unroll
                for (int e = 0; e < 8; ++e) s_acc[j][e] = fmaf(wgt, uh[j][e], s_acc[j][e]);
            }
        } else {
            const float wgt = 1.f / 32.f;
#pragma unroll
            for (int j = 0; j < NB; ++j)
#pragma unroll
                for (int e = 0; e < 8; ++e) s_acc[j][e] = fmaf(wgt, uh[j][e], s_acc[j][e]);
        }
    };

    // 9 unrolled, barrier-free iterations (A/B x-buffer alternation)
    body(xnA, xnB, 0);
    body(xnB, xnA, 1);
    body(xnA, xnB, 2);
    body(xnB, xnA, 3);
    body(xnA, xnB, 4);
    body(xnB, xnA, 5);
    body(xnA, xnB, 6);
    body(xnB, xnA, 7);
    body(xnA, xnB, 8);

    // ---- write partial s ----
    if (!use_atomic) {
        __half* sp = (__half*)s_part;
#pragma unroll
        for (int j = 0; j < NB; ++j) {
            __half* base = sp + (((size_t)ic * BATCH + (b0 + j)) * NC + c) * NE + e0;
            union { __half2 h2v[4]; uint4 u; } pk;
#pragma unroll
            for (int q = 0; q < 4; ++q)
                pk.h2v[q] = __floats2half2_rn(s_acc[j][2*q], s_acc[j][2*q+1]);
            *(uint4*)base = pk.u;
        }
    } else {
        float* sp = (float*)s_part;
        const int slice = ic & (nslice - 1);
#pragma unroll
        for (int j = 0; j < NB; ++j) {
            float* base = sp + (((size_t)slice * BATCH + (b0 + j)) * NC + c) * NE + e0;
#pragma unroll
            for (int e = 0; e < 8; ++e) atomicAdd(base + e, s_acc[j][e]);
        }
    }
}

// ---------------------------------------------------------------------------
// squash: reduce slices (fp16 plain or fp32 atomic layout), squash, update
// o_sum / write output. Each thread owns an e-pair; DPP e-reduction.
// ---------------------------------------------------------------------------
__global__ __launch_bounds__(SQ_THREADS)
void squash_kernel(void* __restrict__ s_part, float* __restrict__ o_sum,
                   float* __restrict__ out, int iter, int nslice, int use_atomic)
{
    const int base2 = (blockIdx.x * SQ_THREADS + threadIdx.x) * 2;  // element pair

    float a0 = 0.f, a1 = 0.f;
    if (!use_atomic) {
        const __half* sp = (const __half*)s_part;
#pragma unroll 8
        for (int k = 0; k < nslice; ++k) {
            __half2 v = *(const __half2*)(sp + (size_t)k * (BATCH * NC * NE) + base2);
            a0 += __low2float(v);
            a1 += __high2float(v);
        }
    } else {
        float* sp = (float*)s_part;
        for (int k = 0; k < nslice; ++k) {
            float2 v = *(float2*)(sp + (size_t)k * (BATCH * NC * NE) + base2);
            a0 += v.x; a1 += v.y;
            *(float2*)(sp + (size_t)k * (BATCH * NC * NE) + base2) = make_float2(0.f, 0.f);
        }
    }

    float q = sum_over_e8(a0 * a0 + a1 * a1);
    // scale = s2/(1+s2)/sqrt(s2) == sqrt(s2)/(1+s2)
    float scale = sqrtf(q) / (1.f + q);
    float o0 = scale * a0, o1 = scale * a1;

    if (iter == NROUT - 1) {
        *(float2*)(out + base2) = make_float2(o0, o1);
    } else if (iter == 0) {
        *(float2*)(o_sum + base2) = make_float2(o0, o1);
    } else {
        float2 prev = *(float2*)(o_sum + base2);
        *(float2*)(o_sum + base2) = make_float2(prev.x + o0, prev.y + o1);
    }
}

extern "C" void kernel_launch(void* const* d_in, const int* in_sizes, int n_in,
                              void* d_out, int out_size, void* d_ws, size_t ws_size,
                              hipStream_t stream) {
    const float* x = (const float*)d_in[0];   // [128,1152,8]
    const float* W = (const float*)d_in[1];   // [1152,32,8,16]
    float* out = (float*)d_out;               // [128,32,16]

    const size_t slice_elems = (size_t)BATCH * NC * NE;   // 65536

    float* o_sum  = (float*)d_ws;
    void*  s_part = (void*)(o_sum + slice_elems);

    // fp16 plain path: 128 slices x 128 KB + 256 KB o_sum = 16.64 MB
    int nslice, use_atomic;
    if (ws_size >= slice_elems * sizeof(float) + (size_t)ISPLIT * slice_elems * sizeof(__half)) {
        nslice = ISPLIT; use_atomic = 0;
    } else if (ws_size >= slice_elems * sizeof(float) * (32 + 1)) {
        nslice = 32; use_atomic = 1;
    } else {
        nslice = 8; use_atomic = 1;
    }

    if (use_atomic)
        (void)hipMemsetAsync(s_part, 0, slice_elems * sizeof(float) * nslice, stream);

    for (int it = 0; it < NROUT; ++it) {
        route_iter_kernel<<<dim3(ISPLIT, BATCH / BT), RT_THREADS, 0, stream>>>(
            x, W, o_sum, s_part, it, nslice, use_atomic);
        squash_kernel<<<(BATCH * NC * NE) / (SQ_THREADS * 2), SQ_THREADS, 0, stream>>>(
            s_part, o_sum, out, it, nslice, use_atomic);
    }
}